// Round 5
// baseline (101.232 us; speedup 1.0000x reference)
//
#include <hip/hip_runtime.h>
#include <hip/hip_bf16.h>

typedef __bf16 bf16t;
typedef bf16t bf16x8 __attribute__((ext_vector_type(8)));
typedef float f32x2 __attribute__((ext_vector_type(2)));
typedef float f32x4 __attribute__((ext_vector_type(4)));
typedef float f32x16 __attribute__((ext_vector_type(16)));
typedef unsigned short u16x8 __attribute__((ext_vector_type(8)));
typedef unsigned int u32x4 __attribute__((ext_vector_type(4)));

#define NB 2
#define NQ 2048
#define NK 2048
#define NH 16
#define ND 64
#define HD (NH * ND) /* 1024 */
#define KVBLK 64
// (1/sqrt(64)) * log2(e): fold scale + base-2 conversion into Q.
#define SCALE_LOG2E 0.18033688011112042f
#define RESCALE_THR 8.0f

// 1024-thread blocks: 4 KV-split groups x 4 q-waves (32 q each) = 128 q/block.
// Group g processes KV tiles t == g (mod 4) with its own double-buffered
// K / V^T LDS (XOR-swizzled); per-wave math = R4 (32x32x16 swapped QK^T,
// in-register softmax via cvt_pk + permlane32_swap, defer-max). Epilogue
// merges the 4 partial (m,l,o) states through the freed staging LDS.
// bid remap keeps XCD = bid&7 while alternating batches within each XCD.
__device__ inline unsigned cvt_pk_bf16(float a, float b) {
    unsigned r;
    asm("v_cvt_pk_bf16_f32 %0, %1, %2" : "=v"(r) : "v"(a), "v"(b));
    return r;  // lo16 = bf16(a), hi16 = bf16(b)
}

__device__ inline void plswap(unsigned& a, unsigned& b) {
#if __has_builtin(__builtin_amdgcn_permlane32_swap)
    auto r = __builtin_amdgcn_permlane32_swap(a, b, false, false);
    a = r[0]; b = r[1];
#else
    const unsigned as = __shfl_xor((int)a, 32);
    const unsigned bs = __shfl_xor((int)b, 32);
    const bool hi = (threadIdx.x & 32) != 0;
    const unsigned na = hi ? bs : a;
    const unsigned nb = hi ? b : as;
    a = na; b = nb;
#endif
}

__global__ __launch_bounds__(1024)
void scan_attn(const float* __restrict__ qs, const float* __restrict__ ks,
               const float* __restrict__ vs, const int* __restrict__ vlen,
               float* __restrict__ out)
{
    const int bid = blockIdx.x;
    // XCD = bid&7 (observed dispatch heuristic). Alternate batches along each
    // XCD's queue; bijection over (b, h, qt).
    const int x   = bid & 7;
    const int j   = bid >> 3;
    const int b   = j & 1;
    const int idx = x | ((j >> 1) << 3);   // 0..255
    const int h   = idx & 15;
    const int qt  = idx >> 4;              // 0..15

    const int tid  = threadIdx.x;
    const int wid  = tid >> 6;
    const int g3   = wid >> 2;          // KV-split group 0..3
    const int wq   = wid & 3;           // q-wave within group
    const int lane = tid & 63;
    const int ql   = lane & 31;
    const int hi   = lane >> 5;
    const int swq  = (ql & 7) << 4;     // row-XOR swizzle for fragment reads
    const int gtid = tid & 255;         // thread id within group
    const int q    = qt * 128 + wq * 32 + ql;

    const int nkv    = vlen[b];                    // in [1, NK]
    const int ntiles = (nkv + KVBLK - 1) >> 6;
    const int rem    = nkv & 63;                   // 0 -> last tile is full
    const int tmax   = (ntiles + 3) >> 2;

    const float* qptr = qs + ((size_t)b * NQ + q) * HD + h * ND;
    const float* kptr = ks + (size_t)b * NK * HD + h * ND;
    const float* vptr = vs + (size_t)b * NK * HD + h * ND;

    // [group][buf][ K tile 8KB | V^T tile 8KB ]  = 128 KB
    __shared__ __align__(16) char smem[4][2][16384];

    // ---- Q fragments (B-operand), scale folded in. qf[c]: d = 16c + 8*hi + j
    bf16x8 qf[4];
#pragma unroll
    for (int c = 0; c < 4; ++c) {
        const float* p = qptr + 16 * c + 8 * hi;
        f32x4 lo = *reinterpret_cast<const f32x4*>(p);
        f32x4 h4 = *reinterpret_cast<const f32x4*>(p + 4);
#pragma unroll
        for (int jj = 0; jj < 4; ++jj) {
            qf[c][jj]     = (bf16t)(lo[jj] * SCALE_LOG2E);
            qf[c][4 + jj] = (bf16t)(h4[jj] * SCALE_LOG2E);
        }
    }

    // ---- staging assignment (256 threads of the group stage 64x64 K and V^T)
    const int skr  = gtid >> 2;            // K: k-row 0..63
    const int skc2 = (gtid & 3) << 5;      // K: 32-byte chunk
    const int ksw  = (skr & 7) << 4;
    const int svd  = gtid & 63;            // V: d column (coalesced)
    const int svk2 = (gtid >> 6) << 5;     // V: 16 k-rows -> 32 bytes
    const int vsw  = (svd & 7) << 4;

    f32x4 kreg[4];
    float vreg[16];

    auto load_tile = [&](int kb) {
        const float* kp = kptr + (size_t)(kb + skr) * HD + ((gtid & 3) << 4);
#pragma unroll
        for (int i = 0; i < 4; ++i)
            kreg[i] = *reinterpret_cast<const f32x4*>(kp + 4 * i);
        const float* vp = vptr + (size_t)(kb + ((gtid >> 6) << 4)) * HD + svd;
#pragma unroll
        for (int jj = 0; jj < 16; ++jj)
            vreg[jj] = vp[(size_t)jj * HD];
    };

    auto store_tile = [&](int buf) {
        u16x8 w0, w1;
#pragma unroll
        for (int i = 0; i < 4; ++i)
#pragma unroll
            for (int jj = 0; jj < 4; ++jj) {
                const int e = 4 * i + jj;
                const unsigned short u =
                    __builtin_bit_cast(unsigned short, (bf16t)kreg[i][jj]);
                if (e < 8) w0[e] = u; else w1[e - 8] = u;
            }
        char* kb_ = smem[g3][buf] + skr * 128;
        *reinterpret_cast<u16x8*>(kb_ + (skc2 ^ ksw))        = w0;
        *reinterpret_cast<u16x8*>(kb_ + ((skc2 + 16) ^ ksw)) = w1;

        u16x8 x0, x1;
#pragma unroll
        for (int jj = 0; jj < 16; ++jj) {
            const unsigned short u =
                __builtin_bit_cast(unsigned short, (bf16t)vreg[jj]);
            if (jj < 8) x0[jj] = u; else x1[jj - 8] = u;
        }
        char* vb_ = smem[g3][buf] + 8192 + svd * 128;
        *reinterpret_cast<u16x8*>(vb_ + (svk2 ^ vsw))        = x0;
        *reinterpret_cast<u16x8*>(vb_ + ((svk2 + 16) ^ vsw)) = x1;
    };

    float mrun = -__builtin_inff();
    float lrun = 0.0f;
    f32x16 o[2] = {};

    if (g3 < ntiles) { load_tile(g3 << 6); store_tile(0); }
    __syncthreads();

    int cur = 0;
    for (int i = 0; i < tmax; ++i) {
        const int tile = 4 * i + g3;
        const bool active   = tile < ntiles;
        const bool has_next = tile + 4 < ntiles;
        if (has_next) load_tile((tile + 4) << 6);   // hide under compute

        if (active) {
            const int kb = tile << 6;
            // ---- S^T = K_tile . Q^T (log2 domain). s[h2][r]: q=ql,
            //      k = kb + 32*h2 + (r&3) + 8*(r>>2) + 4*hi
            const char* kbuf = smem[g3][cur];
            f32x16 s[2];
#pragma unroll
            for (int h2 = 0; h2 < 2; ++h2) {
                f32x16 acc = {};
                const char* krow = kbuf + (32 * h2 + ql) * 128;
#pragma unroll
                for (int c = 0; c < 4; ++c) {
                    bf16x8 kf = *reinterpret_cast<const bf16x8*>(
                        krow + ((32 * c + 16 * hi) ^ swq));
                    acc = __builtin_amdgcn_mfma_f32_32x32x16_bf16(kf, qf[c], acc, 0, 0, 0);
                }
                s[h2] = acc;
            }

            // ---- tail mask (only the group owning the last tile)
            if (rem && tile == ntiles - 1) {
                const int krem = nkv - kb;
#pragma unroll
                for (int h2 = 0; h2 < 2; ++h2)
#pragma unroll
                    for (int r = 0; r < 16; ++r)
                        if (32 * h2 + (r & 3) + 8 * (r >> 2) + 4 * hi >= krem)
                            s[h2][r] = -__builtin_inff();
            }

            // ---- online softmax (row = lanes l and l^32)
            float pmax = -__builtin_inff();
#pragma unroll
            for (int h2 = 0; h2 < 2; ++h2)
#pragma unroll
                for (int r = 0; r < 16; ++r) pmax = fmaxf(pmax, s[h2][r]);
            pmax = fmaxf(pmax, __shfl_xor(pmax, 32));

            if (!__all(pmax <= mrun + RESCALE_THR)) {   // defer-max (T13)
                const float mnew  = fmaxf(mrun, pmax);
                const float alpha = exp2f(mrun - mnew);
                lrun *= alpha;
                o[0] *= alpha;
                o[1] *= alpha;
                mrun = mnew;
            }

            float ps = 0.0f;
#pragma unroll
            for (int h2 = 0; h2 < 2; ++h2)
#pragma unroll
                for (int r = 0; r < 16; ++r) {
                    const float pv = exp2f(s[h2][r] - mrun);
                    s[h2][r] = pv;
                    ps += pv;
                }
            ps += __shfl_xor(ps, 32);
            lrun += ps;

            // ---- P -> PV B-fragments in-register (T12)
            bf16x8 pf[4];
#pragma unroll
            for (int c = 0; c < 4; ++c) {
                const int h2 = c >> 1, r0 = (c & 1) * 8;
                unsigned a0 = cvt_pk_bf16(s[h2][r0 + 0], s[h2][r0 + 1]);
                unsigned b0 = cvt_pk_bf16(s[h2][r0 + 4], s[h2][r0 + 5]);
                plswap(a0, b0);
                unsigned a1 = cvt_pk_bf16(s[h2][r0 + 2], s[h2][r0 + 3]);
                unsigned b1 = cvt_pk_bf16(s[h2][r0 + 6], s[h2][r0 + 7]);
                plswap(a1, b1);
                pf[c] = __builtin_bit_cast(bf16x8, (u32x4){a0, a1, b0, b1});
            }

            // ---- O^T += V^T . P^T
            const char* vbuf = smem[g3][cur] + 8192;
#pragma unroll
            for (int dt = 0; dt < 2; ++dt) {
                const char* vrow = vbuf + (32 * dt + ql) * 128;
#pragma unroll
                for (int c = 0; c < 4; ++c) {
                    bf16x8 vf = *reinterpret_cast<const bf16x8*>(
                        vrow + ((32 * c + 16 * hi) ^ swq));
                    o[dt] = __builtin_amdgcn_mfma_f32_32x32x16_bf16(vf, pf[c], o[dt], 0, 0, 0);
                }
            }
        }

        if (has_next) store_tile(cur ^ 1);
        __syncthreads();
        cur ^= 1;
    }

    // ---- merge the 4 groups' (m, l, o) through the freed staging LDS.
    // Groups 1..3 write o (swizzled f32 rows of 128B) + (m,l); group 0 combines.
    {
        char*  mo_base = &smem[0][0][0];
        f32x2* ml      = (f32x2*)(mo_base + 98304);   // 3*4*64 entries
        const int swl  = (lane & 7) << 4;

        if (g3 > 0) {
            const int sidx = ((g3 - 1) * 4 + wq) * 64 + lane;
            char* so = mo_base + sidx * 128;
#pragma unroll
            for (int c = 0; c < 8; ++c) {
                f32x4 w;
#pragma unroll
                for (int e = 0; e < 4; ++e)
                    w[e] = (c < 4) ? o[0][4 * c + e] : o[1][4 * (c - 4) + e];
                *reinterpret_cast<f32x4*>(so + ((16 * c) ^ swl)) = w;
            }
            ml[sidx] = (f32x2){mrun, lrun};
        }
        __syncthreads();

        if (g3 == 0) {
            f32x2 mg[3];
            float M = mrun;
#pragma unroll
            for (int g = 0; g < 3; ++g) {
                mg[g] = ml[(g * 4 + wq) * 64 + lane];
                M = fmaxf(M, mg[g][0]);
            }
            const float ws = exp2f(mrun - M);
            float lsum = lrun * ws;
            float wg[3];
#pragma unroll
            for (int g = 0; g < 3; ++g) {
                wg[g] = exp2f(mg[g][0] - M);
                lsum += mg[g][1] * wg[g];
            }
            const float inv = 1.0f / lsum;

            float* op = out + ((size_t)b * NQ + q) * HD + h * ND;
#pragma unroll
            for (int c = 0; c < 8; ++c) {
                f32x4 acc;
#pragma unroll
                for (int e = 0; e < 4; ++e)
                    acc[e] = ((c < 4) ? o[0][4 * c + e] : o[1][4 * (c - 4) + e]) * ws;
#pragma unroll
                for (int g = 0; g < 3; ++g) {
                    f32x4 w = *reinterpret_cast<const f32x4*>(
                        mo_base + ((g * 4 + wq) * 64 + lane) * 128 + ((16 * c) ^ swl));
                    acc += wg[g] * w;
                }
                const int dt = c >> 2, rg = c & 3;
                f32x4 res = acc * inv;
                *reinterpret_cast<f32x4*>(op + 32 * dt + 8 * rg + 4 * hi) = res;
            }
        }
    }
}

extern "C" void kernel_launch(void* const* d_in, const int* in_sizes, int n_in,
                              void* d_out, int out_size, void* d_ws, size_t ws_size,
                              hipStream_t stream)
{
    const float* qs   = (const float*)d_in[0];
    const float* ks   = (const float*)d_in[1];
    const float* vs   = (const float*)d_in[2];
    const int*   vlen = (const int*)d_in[3];
    float* out = (float*)d_out;

    dim3 grid(NB * NH * (NQ / 128));   // 512 blocks
    dim3 block(1024);
    scan_attn<<<grid, block, 0, stream>>>(qs, ks, vs, vlen, out);
}

// Round 6
// 80.058 us; speedup vs baseline: 1.2645x; 1.2645x over previous
//
#include <hip/hip_runtime.h>
#include <hip/hip_bf16.h>

typedef __bf16 bf16t;
typedef bf16t bf16x8 __attribute__((ext_vector_type(8)));
typedef float f32x2 __attribute__((ext_vector_type(2)));
typedef float f32x4 __attribute__((ext_vector_type(4)));
typedef float f32x16 __attribute__((ext_vector_type(16)));
typedef unsigned short u16x8 __attribute__((ext_vector_type(8)));
typedef unsigned int u32x4 __attribute__((ext_vector_type(4)));

#define NB 2
#define NQ 2048
#define NK 2048
#define NH 16
#define ND 64
#define HD (NH * ND) /* 1024 */
#define KVBLK 64
// (1/sqrt(64)) * log2(e): fold scale + base-2 conversion into Q.
#define SCALE_LOG2E 0.18033688011112042f
#define RESCALE_THR 8.0f

// 512-thread blocks: 2 KV-split groups x 4 q-waves (32 q each) = 128 q/block.
// Group g processes KV tiles t == g (mod 2) with its own double-buffered
// K / V^T LDS (XOR-swizzled). Per-wave math = R4 (32x32x16 swapped QK^T,
// in-register softmax via cvt_pk + permlane32_swap, defer-max). Epilogue:
// 2-way (m,l,o) merge through freed staging LDS.
// LDS 64KB -> 2 blocks/CU; __launch_bounds__(512,4) caps VGPR at 128
// (R4's identical per-wave body compiled to 120) -> 4 waves/SIMD, no spills.
__device__ inline unsigned cvt_pk_bf16(float a, float b) {
    unsigned r;
    asm("v_cvt_pk_bf16_f32 %0, %1, %2" : "=v"(r) : "v"(a), "v"(b));
    return r;  // lo16 = bf16(a), hi16 = bf16(b)
}

__device__ inline void plswap(unsigned& a, unsigned& b) {
#if __has_builtin(__builtin_amdgcn_permlane32_swap)
    auto r = __builtin_amdgcn_permlane32_swap(a, b, false, false);
    a = r[0]; b = r[1];
#else
    const unsigned as = __shfl_xor((int)a, 32);
    const unsigned bs = __shfl_xor((int)b, 32);
    const bool hi = (threadIdx.x & 32) != 0;
    const unsigned na = hi ? bs : a;
    const unsigned nb = hi ? b : as;
    a = na; b = nb;
#endif
}

__global__ __launch_bounds__(512, 4)
void scan_attn(const float* __restrict__ qs, const float* __restrict__ ks,
               const float* __restrict__ vs, const int* __restrict__ vlen,
               float* __restrict__ out)
{
    const int bid = blockIdx.x;
    // XCD = bid&7 (dispatch heuristic). Alternate batches along each XCD's
    // queue; bijection over (b, h, qt).
    const int x   = bid & 7;
    const int j   = bid >> 3;
    const int b   = j & 1;
    const int idx = x | ((j >> 1) << 3);   // 0..255
    const int h   = idx & 15;
    const int qt  = idx >> 4;              // 0..15

    const int tid  = threadIdx.x;
    const int wid  = tid >> 6;
    const int g2   = wid >> 2;          // KV-split group 0..1
    const int wq   = wid & 3;           // q-wave within group
    const int lane = tid & 63;
    const int ql   = lane & 31;
    const int hi   = lane >> 5;
    const int swq  = (ql & 7) << 4;     // row-XOR swizzle for fragment reads
    const int gtid = tid & 255;         // thread id within group
    const int q    = qt * 128 + wq * 32 + ql;

    const int nkv    = vlen[b];                    // in [1, NK]
    const int ntiles = (nkv + KVBLK - 1) >> 6;
    const int rem    = nkv & 63;                   // 0 -> last tile is full
    const int tmax   = (ntiles + 1) >> 1;

    const float* qptr = qs + ((size_t)b * NQ + q) * HD + h * ND;
    const float* kptr = ks + (size_t)b * NK * HD + h * ND;
    const float* vptr = vs + (size_t)b * NK * HD + h * ND;

    // [group][buf][ K tile 8KB | V^T tile 8KB ]  = 64 KB
    __shared__ __align__(16) char smem[2][2][16384];

    // ---- Q fragments (B-operand), scale folded in. qf[c]: d = 16c + 8*hi + j
    bf16x8 qf[4];
#pragma unroll
    for (int c = 0; c < 4; ++c) {
        const float* p = qptr + 16 * c + 8 * hi;
        f32x4 lo = *reinterpret_cast<const f32x4*>(p);
        f32x4 h4 = *reinterpret_cast<const f32x4*>(p + 4);
#pragma unroll
        for (int jj = 0; jj < 4; ++jj) {
            qf[c][jj]     = (bf16t)(lo[jj] * SCALE_LOG2E);
            qf[c][4 + jj] = (bf16t)(h4[jj] * SCALE_LOG2E);
        }
    }

    // ---- staging assignment (256 threads of the group stage 64x64 K and V^T)
    const int skr  = gtid >> 2;            // K: k-row 0..63
    const int skc2 = (gtid & 3) << 5;      // K: 32-byte chunk
    const int ksw  = (skr & 7) << 4;
    const int svd  = gtid & 63;            // V: d column (coalesced)
    const int svk2 = (gtid >> 6) << 5;     // V: 16 k-rows -> 32 bytes
    const int vsw  = (svd & 7) << 4;

    f32x4 kreg[4];
    float vreg[16];

    auto load_tile = [&](int kb) {
        const float* kp = kptr + (size_t)(kb + skr) * HD + ((gtid & 3) << 4);
#pragma unroll
        for (int i = 0; i < 4; ++i)
            kreg[i] = *reinterpret_cast<const f32x4*>(kp + 4 * i);
        const float* vp = vptr + (size_t)(kb + ((gtid >> 6) << 4)) * HD + svd;
#pragma unroll
        for (int jj = 0; jj < 16; ++jj)
            vreg[jj] = vp[(size_t)jj * HD];
    };

    auto store_tile = [&](int buf) {
        u16x8 w0, w1;
#pragma unroll
        for (int i = 0; i < 4; ++i)
#pragma unroll
            for (int jj = 0; jj < 4; ++jj) {
                const int e = 4 * i + jj;
                const unsigned short u =
                    __builtin_bit_cast(unsigned short, (bf16t)kreg[i][jj]);
                if (e < 8) w0[e] = u; else w1[e - 8] = u;
            }
        char* kb_ = smem[g2][buf] + skr * 128;
        *reinterpret_cast<u16x8*>(kb_ + (skc2 ^ ksw))        = w0;
        *reinterpret_cast<u16x8*>(kb_ + ((skc2 + 16) ^ ksw)) = w1;

        u16x8 x0, x1;
#pragma unroll
        for (int jj = 0; jj < 16; ++jj) {
            const unsigned short u =
                __builtin_bit_cast(unsigned short, (bf16t)vreg[jj]);
            if (jj < 8) x0[jj] = u; else x1[jj - 8] = u;
        }
        char* vb_ = smem[g2][buf] + 8192 + svd * 128;
        *reinterpret_cast<u16x8*>(vb_ + (svk2 ^ vsw))        = x0;
        *reinterpret_cast<u16x8*>(vb_ + ((svk2 + 16) ^ vsw)) = x1;
    };

    float mrun = -__builtin_inff();
    float lrun = 0.0f;
    f32x16 o[2] = {};

    if (g2 < ntiles) { load_tile(g2 << 6); store_tile(0); }
    __syncthreads();

    int cur = 0;
    for (int i = 0; i < tmax; ++i) {
        const int tile = 2 * i + g2;
        const bool active   = tile < ntiles;
        const bool has_next = tile + 2 < ntiles;
        if (has_next) load_tile((tile + 2) << 6);   // hide under compute

        if (active) {
            const int kb = tile << 6;
            // ---- S^T = K_tile . Q^T (log2 domain). s[h2][r]: q=ql,
            //      k = kb + 32*h2 + (r&3) + 8*(r>>2) + 4*hi
            const char* kbuf = smem[g2][cur];
            f32x16 s[2];
#pragma unroll
            for (int h2 = 0; h2 < 2; ++h2) {
                f32x16 acc = {};
                const char* krow = kbuf + (32 * h2 + ql) * 128;
#pragma unroll
                for (int c = 0; c < 4; ++c) {
                    bf16x8 kf = *reinterpret_cast<const bf16x8*>(
                        krow + ((32 * c + 16 * hi) ^ swq));
                    acc = __builtin_amdgcn_mfma_f32_32x32x16_bf16(kf, qf[c], acc, 0, 0, 0);
                }
                s[h2] = acc;
            }

            // ---- tail mask (only the group owning the last tile)
            if (rem && tile == ntiles - 1) {
                const int krem = nkv - kb;
#pragma unroll
                for (int h2 = 0; h2 < 2; ++h2)
#pragma unroll
                    for (int r = 0; r < 16; ++r)
                        if (32 * h2 + (r & 3) + 8 * (r >> 2) + 4 * hi >= krem)
                            s[h2][r] = -__builtin_inff();
            }

            // ---- online softmax (row = lanes l and l^32)
            float pmax = -__builtin_inff();
#pragma unroll
            for (int h2 = 0; h2 < 2; ++h2)
#pragma unroll
                for (int r = 0; r < 16; ++r) pmax = fmaxf(pmax, s[h2][r]);
            pmax = fmaxf(pmax, __shfl_xor(pmax, 32));

            if (!__all(pmax <= mrun + RESCALE_THR)) {   // defer-max (T13)
                const float mnew  = fmaxf(mrun, pmax);
                const float alpha = exp2f(mrun - mnew);
                lrun *= alpha;
                o[0] *= alpha;
                o[1] *= alpha;
                mrun = mnew;
            }

            float ps = 0.0f;
#pragma unroll
            for (int h2 = 0; h2 < 2; ++h2)
#pragma unroll
                for (int r = 0; r < 16; ++r) {
                    const float pv = exp2f(s[h2][r] - mrun);
                    s[h2][r] = pv;
                    ps += pv;
                }
            ps += __shfl_xor(ps, 32);
            lrun += ps;

            // ---- P -> PV B-fragments in-register (T12)
            bf16x8 pf[4];
#pragma unroll
            for (int c = 0; c < 4; ++c) {
                const int h2 = c >> 1, r0 = (c & 1) * 8;
                unsigned a0 = cvt_pk_bf16(s[h2][r0 + 0], s[h2][r0 + 1]);
                unsigned b0 = cvt_pk_bf16(s[h2][r0 + 4], s[h2][r0 + 5]);
                plswap(a0, b0);
                unsigned a1 = cvt_pk_bf16(s[h2][r0 + 2], s[h2][r0 + 3]);
                unsigned b1 = cvt_pk_bf16(s[h2][r0 + 6], s[h2][r0 + 7]);
                plswap(a1, b1);
                pf[c] = __builtin_bit_cast(bf16x8, (u32x4){a0, a1, b0, b1});
            }

            // ---- O^T += V^T . P^T
            const char* vbuf = smem[g2][cur] + 8192;
#pragma unroll
            for (int dt = 0; dt < 2; ++dt) {
                const char* vrow = vbuf + (32 * dt + ql) * 128;
#pragma unroll
                for (int c = 0; c < 4; ++c) {
                    bf16x8 vf = *reinterpret_cast<const bf16x8*>(
                        vrow + ((32 * c + 16 * hi) ^ swq));
                    o[dt] = __builtin_amdgcn_mfma_f32_32x32x16_bf16(vf, pf[c], o[dt], 0, 0, 0);
                }
            }
        }

        if (has_next) store_tile(cur ^ 1);
        __syncthreads();
        cur ^= 1;
    }

    // ---- 2-way merge of (m, l, o) through the freed staging LDS.
    // Group 1 writes its state; group 0 combines, normalizes, stores.
    {
        char*  mo_base = &smem[0][0][0];
        f32x2* ml      = (f32x2*)(mo_base + 32768);   // 256 entries
        const int swl  = (lane & 7) << 4;
        const int sidx = wq * 64 + lane;

        if (g2 == 1) {
            char* so = mo_base + sidx * 128;
#pragma unroll
            for (int c = 0; c < 8; ++c) {
                f32x4 w;
#pragma unroll
                for (int e = 0; e < 4; ++e)
                    w[e] = (c < 4) ? o[0][4 * c + e] : o[1][4 * (c - 4) + e];
                *reinterpret_cast<f32x4*>(so + ((16 * c) ^ swl)) = w;
            }
            ml[sidx] = (f32x2){mrun, lrun};
        }
        __syncthreads();

        if (g2 == 0) {
            const f32x2 mg = ml[sidx];
            const float M  = fmaxf(mrun, mg[0]);
            const float ws = exp2f(mrun - M);
            const float wg = exp2f(mg[0] - M);      // 0 if partner had no tiles
            const float inv = 1.0f / (lrun * ws + mg[1] * wg);

            float* op = out + ((size_t)b * NQ + q) * HD + h * ND;
#pragma unroll
            for (int c = 0; c < 8; ++c) {
                f32x4 w = *reinterpret_cast<const f32x4*>(
                    mo_base + sidx * 128 + ((16 * c) ^ swl));
                f32x4 acc;
#pragma unroll
                for (int e = 0; e < 4; ++e)
                    acc[e] = (((c < 4) ? o[0][4 * c + e] : o[1][4 * (c - 4) + e]) * ws
                              + wg * w[e]) * inv;
                const int dt = c >> 2, rg = c & 3;
                *reinterpret_cast<f32x4*>(op + 32 * dt + 8 * rg + 4 * hi) = acc;
            }
        }
    }
}

extern "C" void kernel_launch(void* const* d_in, const int* in_sizes, int n_in,
                              void* d_out, int out_size, void* d_ws, size_t ws_size,
                              hipStream_t stream)
{
    const float* qs   = (const float*)d_in[0];
    const float* ks   = (const float*)d_in[1];
    const float* vs   = (const float*)d_in[2];
    const int*   vlen = (const int*)d_in[3];
    float* out = (float*)d_out;

    dim3 grid(NB * NH * (NQ / 128));   // 512 blocks
    dim3 block(512);
    scan_attn<<<grid, block, 0, stream>>>(qs, ks, vs, vlen, out);
}

// Round 7
// 61.880 us; speedup vs baseline: 1.6359x; 1.2938x over previous
//
#include <hip/hip_runtime.h>
#include <hip/hip_bf16.h>

typedef __bf16 bf16t;
typedef bf16t bf16x8 __attribute__((ext_vector_type(8)));
typedef float f32x2 __attribute__((ext_vector_type(2)));
typedef float f32x4 __attribute__((ext_vector_type(4)));
typedef float f32x16 __attribute__((ext_vector_type(16)));
typedef unsigned short u16x8 __attribute__((ext_vector_type(8)));
typedef unsigned int u32x4 __attribute__((ext_vector_type(4)));

#define NB 2
#define NQ 2048
#define NK 2048
#define NH 16
#define ND 64
#define HD (NH * ND) /* 1024 */
#define KVBLK 64
// (1/sqrt(64)) * log2(e): fold scale + base-2 conversion into Q.
#define SCALE_LOG2E 0.18033688011112042f
#define RESCALE_THR 8.0f

// 512-thread blocks: 2 KV-split groups x 4 q-waves (32 q each) = 128 q/block.
// Group g processes KV tiles t == g (mod 2) with its own double-buffered
// K / V^T LDS (XOR-swizzled). Per-wave math: 32x32x16 swapped QK^T,
// in-register softmax via cvt_pk + permlane32_swap, defer-max. Epilogue:
// 2-way (m,l,o) merge through freed staging LDS.
//
// __launch_bounds__(512, 2): the 2nd arg is min BLOCKS/CU (CUDA semantics —
// verified R5/R6: arg=4 @512thr -> waves-per-eu=8 -> VGPR capped 64 -> spills,
// WRITE_SIZE 61MB). arg=2 -> 4 waves/EU -> 128 VGPR cap, body needs ~120.
// LDS 64KB -> exactly 2 blocks/CU -> 16 waves/CU sustained.
__device__ inline unsigned cvt_pk_bf16(float a, float b) {
    unsigned r;
    asm("v_cvt_pk_bf16_f32 %0, %1, %2" : "=v"(r) : "v"(a), "v"(b));
    return r;  // lo16 = bf16(a), hi16 = bf16(b)
}

__device__ inline void plswap(unsigned& a, unsigned& b) {
#if __has_builtin(__builtin_amdgcn_permlane32_swap)
    auto r = __builtin_amdgcn_permlane32_swap(a, b, false, false);
    a = r[0]; b = r[1];
#else
    const unsigned as = __shfl_xor((int)a, 32);
    const unsigned bs = __shfl_xor((int)b, 32);
    const bool hi = (threadIdx.x & 32) != 0;
    const unsigned na = hi ? bs : a;
    const unsigned nb = hi ? b : as;
    a = na; b = nb;
#endif
}

__global__ __launch_bounds__(512, 2)
void scan_attn(const float* __restrict__ qs, const float* __restrict__ ks,
               const float* __restrict__ vs, const int* __restrict__ vlen,
               float* __restrict__ out)
{
    const int bid = blockIdx.x;
    // XCD = bid&7 (dispatch heuristic). Alternate batches along each XCD's
    // queue; bijection over (b, h, qt).
    const int x   = bid & 7;
    const int j   = bid >> 3;
    const int b   = j & 1;
    const int idx = x | ((j >> 1) << 3);   // 0..255
    const int h   = idx & 15;
    const int qt  = idx >> 4;              // 0..15

    const int tid  = threadIdx.x;
    const int wid  = tid >> 6;
    const int g2   = wid >> 2;          // KV-split group 0..1
    const int wq   = wid & 3;           // q-wave within group
    const int lane = tid & 63;
    const int ql   = lane & 31;
    const int hi   = lane >> 5;
    const int swq  = (ql & 7) << 4;     // row-XOR swizzle for fragment reads
    const int gtid = tid & 255;         // thread id within group
    const int q    = qt * 128 + wq * 32 + ql;

    const int nkv    = vlen[b];                    // in [1, NK]
    const int ntiles = (nkv + KVBLK - 1) >> 6;
    const int rem    = nkv & 63;                   // 0 -> last tile is full
    const int tmax   = (ntiles + 1) >> 1;

    const float* qptr = qs + ((size_t)b * NQ + q) * HD + h * ND;
    const float* kptr = ks + (size_t)b * NK * HD + h * ND;
    const float* vptr = vs + (size_t)b * NK * HD + h * ND;

    // [group][buf][ K tile 8KB | V^T tile 8KB ]  = 64 KB
    __shared__ __align__(16) char smem[2][2][16384];

    // ---- Q fragments (B-operand), scale folded in. qf[c]: d = 16c + 8*hi + j
    bf16x8 qf[4];
#pragma unroll
    for (int c = 0; c < 4; ++c) {
        const float* p = qptr + 16 * c + 8 * hi;
        f32x4 lo = *reinterpret_cast<const f32x4*>(p);
        f32x4 h4 = *reinterpret_cast<const f32x4*>(p + 4);
#pragma unroll
        for (int jj = 0; jj < 4; ++jj) {
            qf[c][jj]     = (bf16t)(lo[jj] * SCALE_LOG2E);
            qf[c][4 + jj] = (bf16t)(h4[jj] * SCALE_LOG2E);
        }
    }

    // ---- staging assignment (256 threads of the group stage 64x64 K and V^T)
    const int skr  = gtid >> 2;            // K: k-row 0..63
    const int skc2 = (gtid & 3) << 5;      // K: 32-byte chunk
    const int ksw  = (skr & 7) << 4;
    const int svd  = gtid & 63;            // V: d column (coalesced)
    const int svk2 = (gtid >> 6) << 5;     // V: 16 k-rows -> 32 bytes
    const int vsw  = (svd & 7) << 4;

    f32x4 kreg[4];
    float vreg[16];

    auto load_tile = [&](int kb) {
        const float* kp = kptr + (size_t)(kb + skr) * HD + ((gtid & 3) << 4);
#pragma unroll
        for (int i = 0; i < 4; ++i)
            kreg[i] = *reinterpret_cast<const f32x4*>(kp + 4 * i);
        const float* vp = vptr + (size_t)(kb + ((gtid >> 6) << 4)) * HD + svd;
#pragma unroll
        for (int jj = 0; jj < 16; ++jj)
            vreg[jj] = vp[(size_t)jj * HD];
    };

    auto store_tile = [&](int buf) {
        u16x8 w0, w1;
#pragma unroll
        for (int i = 0; i < 4; ++i)
#pragma unroll
            for (int jj = 0; jj < 4; ++jj) {
                const int e = 4 * i + jj;
                const unsigned short u =
                    __builtin_bit_cast(unsigned short, (bf16t)kreg[i][jj]);
                if (e < 8) w0[e] = u; else w1[e - 8] = u;
            }
        char* kb_ = smem[g2][buf] + skr * 128;
        *reinterpret_cast<u16x8*>(kb_ + (skc2 ^ ksw))        = w0;
        *reinterpret_cast<u16x8*>(kb_ + ((skc2 + 16) ^ ksw)) = w1;

        u16x8 x0, x1;
#pragma unroll
        for (int jj = 0; jj < 16; ++jj) {
            const unsigned short u =
                __builtin_bit_cast(unsigned short, (bf16t)vreg[jj]);
            if (jj < 8) x0[jj] = u; else x1[jj - 8] = u;
        }
        char* vb_ = smem[g2][buf] + 8192 + svd * 128;
        *reinterpret_cast<u16x8*>(vb_ + (svk2 ^ vsw))        = x0;
        *reinterpret_cast<u16x8*>(vb_ + ((svk2 + 16) ^ vsw)) = x1;
    };

    float mrun = -__builtin_inff();
    float lrun = 0.0f;
    f32x16 o[2] = {};

    if (g2 < ntiles) { load_tile(g2 << 6); store_tile(0); }
    __syncthreads();

    int cur = 0;
    for (int i = 0; i < tmax; ++i) {
        const int tile = 2 * i + g2;
        const bool active   = tile < ntiles;
        const bool has_next = tile + 2 < ntiles;
        if (has_next) load_tile((tile + 2) << 6);   // hide under compute

        if (active) {
            const int kb = tile << 6;
            // ---- S^T = K_tile . Q^T (log2 domain). s[h2][r]: q=ql,
            //      k = kb + 32*h2 + (r&3) + 8*(r>>2) + 4*hi
            const char* kbuf = smem[g2][cur];
            f32x16 s[2];
#pragma unroll
            for (int h2 = 0; h2 < 2; ++h2) {
                f32x16 acc = {};
                const char* krow = kbuf + (32 * h2 + ql) * 128;
#pragma unroll
                for (int c = 0; c < 4; ++c) {
                    bf16x8 kf = *reinterpret_cast<const bf16x8*>(
                        krow + ((32 * c + 16 * hi) ^ swq));
                    acc = __builtin_amdgcn_mfma_f32_32x32x16_bf16(kf, qf[c], acc, 0, 0, 0);
                }
                s[h2] = acc;
            }

            // ---- tail mask (only the group owning the last tile)
            if (rem && tile == ntiles - 1) {
                const int krem = nkv - kb;
#pragma unroll
                for (int h2 = 0; h2 < 2; ++h2)
#pragma unroll
                    for (int r = 0; r < 16; ++r)
                        if (32 * h2 + (r & 3) + 8 * (r >> 2) + 4 * hi >= krem)
                            s[h2][r] = -__builtin_inff();
            }

            // ---- online softmax (row = lanes l and l^32)
            float pmax = -__builtin_inff();
#pragma unroll
            for (int h2 = 0; h2 < 2; ++h2)
#pragma unroll
                for (int r = 0; r < 16; ++r) pmax = fmaxf(pmax, s[h2][r]);
            pmax = fmaxf(pmax, __shfl_xor(pmax, 32));

            if (!__all(pmax <= mrun + RESCALE_THR)) {   // defer-max (T13)
                const float mnew  = fmaxf(mrun, pmax);
                const float alpha = exp2f(mrun - mnew);
                lrun *= alpha;
                o[0] *= alpha;
                o[1] *= alpha;
                mrun = mnew;
            }

            float ps = 0.0f;
#pragma unroll
            for (int h2 = 0; h2 < 2; ++h2)
#pragma unroll
                for (int r = 0; r < 16; ++r) {
                    const float pv = exp2f(s[h2][r] - mrun);
                    s[h2][r] = pv;
                    ps += pv;
                }
            ps += __shfl_xor(ps, 32);
            lrun += ps;

            // ---- P -> PV B-fragments in-register (T12)
            bf16x8 pf[4];
#pragma unroll
            for (int c = 0; c < 4; ++c) {
                const int h2 = c >> 1, r0 = (c & 1) * 8;
                unsigned a0 = cvt_pk_bf16(s[h2][r0 + 0], s[h2][r0 + 1]);
                unsigned b0 = cvt_pk_bf16(s[h2][r0 + 4], s[h2][r0 + 5]);
                plswap(a0, b0);
                unsigned a1 = cvt_pk_bf16(s[h2][r0 + 2], s[h2][r0 + 3]);
                unsigned b1 = cvt_pk_bf16(s[h2][r0 + 6], s[h2][r0 + 7]);
                plswap(a1, b1);
                pf[c] = __builtin_bit_cast(bf16x8, (u32x4){a0, a1, b0, b1});
            }

            // ---- O^T += V^T . P^T
            const char* vbuf = smem[g2][cur] + 8192;
#pragma unroll
            for (int dt = 0; dt < 2; ++dt) {
                const char* vrow = vbuf + (32 * dt + ql) * 128;
#pragma unroll
                for (int c = 0; c < 4; ++c) {
                    bf16x8 vf = *reinterpret_cast<const bf16x8*>(
                        vrow + ((32 * c + 16 * hi) ^ swq));
                    o[dt] = __builtin_amdgcn_mfma_f32_32x32x16_bf16(vf, pf[c], o[dt], 0, 0, 0);
                }
            }
        }

        if (has_next) store_tile(cur ^ 1);
        __syncthreads();
        cur ^= 1;
    }

    // ---- 2-way merge of (m, l, o) through the freed staging LDS.
    // Group 1 writes its state; group 0 combines, normalizes, stores.
    {
        char*  mo_base = &smem[0][0][0];
        f32x2* ml      = (f32x2*)(mo_base + 32768);   // 256 entries
        const int swl  = (lane & 7) << 4;
        const int sidx = wq * 64 + lane;

        if (g2 == 1) {
            char* so = mo_base + sidx * 128;
#pragma unroll
            for (int c = 0; c < 8; ++c) {
                f32x4 w;
#pragma unroll
                for (int e = 0; e < 4; ++e)
                    w[e] = (c < 4) ? o[0][4 * c + e] : o[1][4 * (c - 4) + e];
                *reinterpret_cast<f32x4*>(so + ((16 * c) ^ swl)) = w;
            }
            ml[sidx] = (f32x2){mrun, lrun};
        }
        __syncthreads();

        if (g2 == 0) {
            const f32x2 mg = ml[sidx];
            const float M  = fmaxf(mrun, mg[0]);
            const float ws = exp2f(mrun - M);
            const float wg = exp2f(mg[0] - M);      // 0 if partner had no tiles
            const float inv = 1.0f / (lrun * ws + mg[1] * wg);

            float* op = out + ((size_t)b * NQ + q) * HD + h * ND;
#pragma unroll
            for (int c = 0; c < 8; ++c) {
                f32x4 w = *reinterpret_cast<const f32x4*>(
                    mo_base + sidx * 128 + ((16 * c) ^ swl));
                f32x4 acc;
#pragma unroll
                for (int e = 0; e < 4; ++e)
                    acc[e] = (((c < 4) ? o[0][4 * c + e] : o[1][4 * (c - 4) + e]) * ws
                              + wg * w[e]) * inv;
                const int dt = c >> 2, rg = c & 3;
                *reinterpret_cast<f32x4*>(op + 32 * dt + 8 * rg + 4 * hi) = acc;
            }
        }
    }
}

extern "C" void kernel_launch(void* const* d_in, const int* in_sizes, int n_in,
                              void* d_out, int out_size, void* d_ws, size_t ws_size,
                              hipStream_t stream)
{
    const float* qs   = (const float*)d_in[0];
    const float* ks   = (const float*)d_in[1];
    const float* vs   = (const float*)d_in[2];
    const int*   vlen = (const int*)d_in[3];
    float* out = (float*)d_out;

    dim3 grid(NB * NH * (NQ / 128));   // 512 blocks
    dim3 block(512);
    scan_attn<<<grid, block, 0, stream>>>(qs, ks, vs, vlen, out);
}